// Round 5
// baseline (704.181 us; speedup 1.0000x reference)
//
#include <hip/hip_runtime.h>
#include <math.h>

constexpr int B = 32, N = 1024, ND = 8, FEAT = 2048, WVD = 300;
constexpr int E = 20000, T = 2, STEPS = 5;
constexpr int NDIM = N * ND;            // 8192
constexpr int H1 = 512;
constexpr int W1C = FEAT + WVD;         // 2348
constexpr int EMB = 50;
constexpr int RC = EMB * ND * ND;       // 3200
constexpr int SEG = 16;
constexpr int SEGLEN = E / SEG;         // 1250 (NOT a multiple of 64 — guard!)
constexpr int GRP = 8;

// fused-kernel block ranges
constexpr int G_SEGH = T * N * SEG / 4;   // 8192
constexpr int G_A    = 128 * 32;          // 4096
constexpr int G_W1T  = 16 * 10;           // 160
constexpr int G_EMBS = 256;
constexpr int F1_TOT = G_SEGH + G_A + G_W1T + G_EMBS;

constexpr int G_WV2  = 256;               // (2 c-tiles) x (128 n-tiles)
constexpr int G_AHAT = 13 * 128 * 2;      // 3328
constexpr int F2_TOT = 1 + G_WV2 + G_AHAT;

constexpr int G_SCAT = T * N * SEG / 4;   // 8192
constexpr int G_INP  = B * N / 4;         // 8192
constexpr int F3_TOT = G_SCAT + G_INP;

constexpr int G_WTS  = 2 * N;             // 2048
constexpr int G_TR   = NDIM / 64;         // 128
constexpr int F4_TOT = G_WTS + G_TR;

constexpr int NBLK_STEPS = 512;

// ============ F1: seghist | A | W1-transpose | embs (all independent) ============
__global__ __launch_bounds__(256) void k_f1(
        const int* eu, int* segcnt,
        const float* inp, const float* W1, float* Ab, float* W1T,
        const float* wv, const float* We, const float* be, float* embs) {
    __shared__ float smem[32 * 33];
    int tid = threadIdx.x;
    int blk = blockIdx.x;
    if (blk < G_SEGH) {
        int wid = blk * 4 + (tid >> 6);
        int lane = tid & 63;
        int t = wid >> 14, u = (wid >> 4) & (N - 1), seg = wid & (SEG - 1);
        const int* eut = eu + t * E;
        int e0 = seg * SEGLEN, e1 = e0 + SEGLEN, cnt = 0;
        for (int c = e0; c < e1; c += 64) {
            int e = c + lane;
            bool ok = (e < e1) && (eut[e] == u);
            cnt += __popcll(__ballot(ok));
        }
        if (lane == 0) segcnt[wid] = cnt;
    } else if (blk < G_SEGH + G_A) {
        int lb = blk - G_SEGH;
        int lane = tid & 63, w = tid >> 6;
        int c = (lb & 127) * 4 + w, b = lb >> 7;
        const float* xr = inp + (size_t)b * FEAT;
        const float* wr = W1 + (size_t)c * W1C;
        float acc = 0.f;
#pragma unroll
        for (int i = 0; i < FEAT / 64; i++) {
            int k = i * 64 + lane;
            acc += xr[k] * wr[k];
        }
        for (int m = 32; m; m >>= 1) acc += __shfl_xor(acc, m, 64);
        if (lane == 0) Ab[b * H1 + c] = acc;
    } else if (blk < G_SEGH + G_A + G_W1T) {
        int lb = blk - G_SEGH - G_A;
        int c0 = (lb % 16) * 32, k0 = (lb / 16) * 32;
        float (*tile)[33] = (float(*)[33])smem;
        int kl = tid & 31, cl4 = tid >> 5;
#pragma unroll
        for (int p = 0; p < 4; p++) {
            int c = cl4 + p * 8;
            int k = k0 + kl;
            if (k < WVD) tile[c][kl] = W1[(size_t)(c0 + c) * W1C + FEAT + k];
        }
        __syncthreads();
        int cl = tid & 31, kl4 = tid >> 5;
#pragma unroll
        for (int p = 0; p < 4; p++) {
            int kk = kl4 + p * 8;
            int k = k0 + kk;
            if (k < WVD) W1T[(size_t)k * H1 + c0 + cl] = tile[cl][kk];
        }
    } else {
        int lb = blk - G_SEGH - G_A - G_W1T;
        int i = lb * 256 + tid;
        int n = i >> 6, c = i & 63;
        if (c >= EMB) return;
        const float* xr = wv + (size_t)n * WVD;
        const float* wr = We + (size_t)c * WVD;
        float acc = be[c];
        for (int k = 0; k < WVD; k++) acc += xr[k] * wr[k];
        embs[n * EMB + c] = acc;
    }
}

// ============ F2: seg-scan+global-scan (1 block) | Wv GEMM | Ahat GEMM x2 ============
__global__ __launch_bounds__(256) void k_f2(
        const int* segcnt, int* segoff, int* counts, int* ptr,
        const float* wv, const float* W1T, float* Wvb,
        const float* embs, const float* RMbase, float* Ahat) {
    __shared__ float smemf[4096];   // 16 KB, aliased per role
    int tid = threadIdx.x, blk = blockIdx.x;
    if (blk == 0) {
        int* sc = (int*)smemf;      // [0..2047] + [2048..4095] ping-pong
        for (int row = tid; row < 2048; row += 256) {
            int acc = 0;
            const int* src = segcnt + row * SEG;
            int* dst = segoff + row * SEG;
#pragma unroll
            for (int s = 0; s < SEG; s++) { dst[s] = acc; acc += src[s]; }
            counts[row] = acc;
            sc[row] = acc;
        }
        __syncthreads();
        int* src = sc; int* dst = sc + 2048;
        for (int st = 1; st < 2048; st <<= 1) {
            for (int j = tid; j < 2048; j += 256)
                dst[j] = src[j] + (j >= st ? src[j - st] : 0);
            __syncthreads();
            int* tmp = src; src = dst; dst = tmp;
        }
        for (int j = tid; j < 2048; j += 256)
            ptr[j] = j ? src[j - 1] : 0;
    } else if (blk <= G_WV2) {
        int lb = blk - 1;
        int c = (lb & 1) * 256 + tid;
        int n0 = (lb >> 1) * 8;
        float (*el)[WVD] = (float(*)[WVD])smemf;
        for (int idx = tid; idx < 8 * WVD; idx += 256)
            el[idx / WVD][idx % WVD] = wv[(size_t)(n0 + idx / WVD) * WVD + idx % WVD];
        __syncthreads();
        float acc[8] = {};
        for (int k = 0; k < WVD; k++) {
            float r = W1T[(size_t)k * H1 + c];
#pragma unroll
            for (int j = 0; j < 8; j++) acc[j] += el[j][k] * r;
        }
#pragma unroll
        for (int j = 0; j < 8; j++) Wvb[(size_t)(n0 + j) * H1 + c] = acc[j];
    } else {
        int lb = blk - 1 - G_WV2;
        int t = lb / 1664, r = lb % 1664;
        int bx = r % 13, by = r / 13;
        const float* RM = RMbase + (size_t)t * EMB * RC;
        float* Ah = Ahat + (size_t)t * N * RC;
        float (*el)[EMB] = (float(*)[EMB])smemf;
        int n0 = by * 8;
        for (int i = tid; i < 8 * EMB; i += 256)
            el[i / EMB][i % EMB] = embs[(n0 + i / EMB) * EMB + i % EMB];
        __syncthreads();
        int m = bx * 256 + tid;
        if (m < RC) {
            float acc[8] = {};
            for (int c = 0; c < EMB; c++) {
                float rr = RM[(size_t)c * RC + m];
#pragma unroll
                for (int j = 0; j < 8; j++) acc[j] += el[j][c] * rr;
            }
#pragma unroll
            for (int j = 0; j < 8; j++) Ah[(size_t)(n0 + j) * RC + m] = acc[j];
        }
    }
}

// ============ F3: scatter | inputnet ============
__global__ __launch_bounds__(256) void k_f3(
        const int* eu, const int* ev, const int* ptr, const int* segoff, int* sv,
        const float* Ab, const float* Wvb, const float* b1,
        const float* W2, const float* b2, float* h0) {
    int tid = threadIdx.x, blk = blockIdx.x;
    if (blk < G_SCAT) {
        int wid = blk * 4 + (tid >> 6);
        int lane = tid & 63;
        int t = wid >> 14, u = (wid >> 4) & (N - 1), seg = wid & (SEG - 1);
        const int* eut = eu + t * E;
        const int* evt = ev + t * E;
        int row = t * N + u;
        int base = ptr[row] + segoff[row * SEG + seg];
        int e0 = seg * SEGLEN, e1 = e0 + SEGLEN, cnt = 0;
        for (int c = e0; c < e1; c += 64) {
            int e = c + lane;
            bool ok = (e < e1) && (eut[e] == u);
            unsigned long long m = __ballot(ok);
            if (ok) {
                int rank = __popcll(m & ((1ull << lane) - 1));
                sv[base + cnt + rank] = evt[e];
            }
            cnt += __popcll(m);
        }
    } else {
        int lb = blk - G_SCAT;
        int gw = lb * 4 + (tid >> 6);
        int lane = tid & 63;
        int b = gw >> 10, n = gw & (N - 1);
        const float* ar = Ab + b * H1;
        const float* vr = Wvb + n * H1;
        float acc[8] = {};
#pragma unroll
        for (int i = 0; i < H1 / 64; i++) {
            int c = i * 64 + lane;
            float t = ar[c] + vr[c] + b1[c];
            t = fmaxf(t, 0.f);
#pragma unroll
            for (int ki = 0; ki < 8; ki++) acc[ki] += t * W2[ki * H1 + c];
        }
#pragma unroll
        for (int ki = 0; ki < 8; ki++)
            for (int m = 32; m; m >>= 1) acc[ki] += __shfl_xor(acc[ki], m, 64);
        if (lane == 0) {
            float* o = h0 + (size_t)b * NDIM + n * ND;
#pragma unroll
            for (int ki = 0; ki < 8; ki++) o[ki] = acc[ki] + b2[ki];
        }
    }
}

// ============ F4: edge weights (block per (t,u), Ahat in LDS) | h0 transpose ============
__global__ __launch_bounds__(256) void k_f4(
        const int* ptr, const int* counts, const int* sv,
        const float* embs, const float* Ahat, float* wbuf,
        const float* h0, float* sT0) {
    __shared__ float smemf[RC];  // 12.8 KB; tr needs 64*33=2112 < RC
    int tid = threadIdx.x, blk = blockIdx.x;
    if (blk < G_WTS) {
        int t = blk >> 10, u = blk & (N - 1);
        float* AL = smemf;
        int base = ptr[t * N + u], cnt = counts[t * N + u];
        for (int idx = tid; idx < RC; idx += 256)
            AL[idx] = Ahat[((size_t)t * N + u) * RC + idx];
        __syncthreads();
        int wv_ = tid >> 6, k = tid & 63;
        for (int i = wv_; i < cnt; i += 4) {
            int slot = base + i;
            int v = sv[slot];
            const float* vr = embs + v * EMB;
            float acc = 0.f;
#pragma unroll 10
            for (int d = 0; d < EMB; d++) acc += vr[d] * AL[d * 64 + k];
            wbuf[(size_t)slot * 64 + k] = acc;
        }
    } else {
        int lb = blk - G_WTS;
        float (*tile)[33] = (float(*)[33])smemf;
        int i0 = lb * 64;
        int il = tid & 63, bl = tid >> 6;
#pragma unroll
        for (int p = 0; p < 8; p++) {
            int b = bl + p * 4;
            tile[il][b] = h0[(size_t)b * NDIM + i0 + il];
        }
        __syncthreads();
        int bw = tid & 31, iw = tid >> 5;
#pragma unroll
        for (int p = 0; p < 8; p++) {
            int i = iw + p * 8;
            sT0[(size_t)(i0 + i) * B + bw] = tile[i][bw];
        }
    }
}

// ============ norms -> reciprocals; also zero the grid-barrier counter ============
__global__ __launch_bounds__(256) void k_norm(
        const int* ptr, const int* counts, const float* wbuf,
        float* inorm, unsigned* bar) {
    if (blockIdx.x == 0 && threadIdx.x == 0) bar[0] = 0u;
    int u = (blockIdx.x * 256 + threadIdx.x) >> 6;
    int lane = threadIdx.x & 63;
    int ki = lane >> 3, kj = lane & 7;
    float acc = 0.f;
    for (int t = 0; t < T; t++) {
        int base = ptr[t * N + u], c = counts[t * N + u];
        for (int i = 0; i < c; i++) {
            float x = wbuf[(size_t)(base + i) * 64 + lane];
            acc += x * x;
        }
    }
    acc += __shfl_xor(acc, 1, 64);
    acc += __shfl_xor(acc, 2, 64);
    acc += __shfl_xor(acc, 4, 64);
    if (kj == 0) {
        float nv = sqrtf(acc);
        if (nv == 0.f) nv = 1.f;
        inorm[u * ND + ki] = 1.0f / nv;
    }
}

// ============ persistent propagation: 5 steps + outnet, manual grid barrier ============
__device__ inline void gbar(unsigned* bar, unsigned target) {
    __syncthreads();                       // compiler drains vmcnt before s_barrier
    if (threadIdx.x == 0) {
        __threadfence();                   // agent-scope release: L2 writeback
        atomicAdd(bar, 1u);
        while (atomicAdd(bar, 0u) < target) __builtin_amdgcn_s_sleep(2);
        __threadfence();                   // acquire
    }
    __syncthreads();
}

__global__ __launch_bounds__(256, 2) void k_steps(
        const int* ptr, const int* counts, const int* sv,
        const float* wbuf, const float* inorm, float* sT,
        const float* W_ih, const float* W_hh, const float* b_ih, const float* b_hh,
        const float* Wo1, const float* bo1, const float* Wo2, const float* bo2,
        float* out, unsigned* bar) {
    __shared__ float wl[GRP][64];
    __shared__ float hvl[GRP][8][32];
    __shared__ float wih[192], whh[192];
    __shared__ float w1s[160], b1s[20], w2s[20];
    __shared__ float res[6][33];
    int tid = threadIdx.x;
    if (tid < 192) { wih[tid] = W_ih[tid]; whh[tid] = W_hh[tid]; }
    if (tid < 160) w1s[tid] = Wo1[tid];
    if (tid < 20) { b1s[tid] = bo1[tid]; w2s[tid] = Wo2[tid]; }
    int ki = tid >> 5, b = tid & 31;

    for (int s = 0; s < STEPS; s++) {
        const float* sIn = sT + (size_t)s * NDIM * B;
        float* sOut = sT + (size_t)(s + 1) * NDIM * B;
        for (int half = 0; half < 2; half++) {
            int u = blockIdx.x + half * NBLK_STEPS;
            float hown = sIn[((size_t)u * 8 + ki) * B + b];
            float acc = 0.f;
            for (int t = 0; t < T; t++) {
                int base = ptr[t * N + u], cnt = counts[t * N + u];
                for (int c0 = 0; c0 < cnt; c0 += GRP) {
                    int nb = min(GRP, cnt - c0);
                    __syncthreads();
#pragma unroll
                    for (int r = 0; r < 2; r++) {
                        int idx = tid + r * 256;
                        int e = idx >> 6, k = idx & 63;
                        float w = 0.f;
                        if (e < nb) {
                            int v = sv[base + c0 + e];
                            w = wbuf[(size_t)(base + c0 + e) * 64 + k]
                                * inorm[v * ND + (k & 7)];
                        }
                        wl[e][k] = w;
                    }
#pragma unroll
                    for (int j = 0; j < GRP; j++) {
                        int vj = (j < nb) ? sv[base + c0 + j] : 0;
                        hvl[j][ki][b] = sIn[((size_t)vj * 8 + ki) * B + b];
                    }
                    __syncthreads();
#pragma unroll
                    for (int j = 0; j < GRP; j++) {
                        const float* wj = &wl[j][ki * 8];
                        const float* hj = &hvl[j][0][b];
#pragma unroll
                        for (int kj = 0; kj < 8; kj++)
                            acc += wj[kj] * hj[kj * 32];
                    }
                }
            }
            float xv = tanhf(acc);
            __syncthreads();
            float* xs = &hvl[0][0][0];
            float* hs = &hvl[2][0][0];
            xs[ki * 32 + b] = xv;
            hs[ki * 32 + b] = hown;
            __syncthreads();
            float gr = b_ih[ki], gz = b_ih[8 + ki], gn = b_ih[16 + ki];
            float hr = b_hh[ki], hz = b_hh[8 + ki], hn = b_hh[16 + ki];
#pragma unroll
            for (int j = 0; j < 8; j++) {
                float xj = xs[j * 32 + b], hj = hs[j * 32 + b];
                gr += wih[ki * 8 + j] * xj;
                gz += wih[(8 + ki) * 8 + j] * xj;
                gn += wih[(16 + ki) * 8 + j] * xj;
                hr += whh[ki * 8 + j] * hj;
                hz += whh[(8 + ki) * 8 + j] * hj;
                hn += whh[(16 + ki) * 8 + j] * hj;
            }
            float r = 1.f / (1.f + expf(-(gr + hr)));
            float z = 1.f / (1.f + expf(-(gz + hz)));
            float nn = tanhf(gn + r * hn);
            float hnew = (1.f - z) * nn + z * hown;
            sOut[((size_t)u * 8 + ki) * B + b] = hnew;
            __syncthreads();
        }
        if (s < STEPS - 1)
            gbar(bar, (unsigned)((s + 1) * NBLK_STEPS));
        // after the last step no barrier: the out-phase below reads only rows
        // this block itself wrote.
    }

    // ---- outnet phase ----
    for (int half = 0; half < 2; half++) {
        int n = blockIdx.x + half * NBLK_STEPS;
        int s6 = tid >> 5, bb = tid & 31;
        float accv = 0.f;
        if (s6 < 6) {
            float x[8];
#pragma unroll
            for (int k = 0; k < 8; k++)
                x[k] = sT[((size_t)s6 * NDIM + n * 8 + k) * B + bb];
            accv = bo2[0];
#pragma unroll
            for (int j = 0; j < 20; j++) {
                float h = b1s[j];
#pragma unroll
                for (int k = 0; k < 8; k++) h += w1s[j * 8 + k] * x[k];
                h = fmaxf(h, 0.f);
                accv += w2s[j] * h;
            }
        }
        __syncthreads();
        if (s6 < 6) res[s6][bb] = accv;
        __syncthreads();
        if (tid < 192) {
            int b_w = tid / 6, s_w = tid - b_w * 6;
            out[(size_t)b_w * ((STEPS + 1) * N) + n * (STEPS + 1) + s_w] = res[s_w][b_w];
        }
    }
}

extern "C" void kernel_launch(void* const* d_in, const int* in_sizes, int n_in,
                              void* d_out, int out_size, void* d_ws, size_t ws_size,
                              hipStream_t stream) {
    const float* inputs   = (const float*)d_in[0];
    const float* wordvecs = (const float*)d_in[1];
    const int*   edge_u   = (const int*)d_in[2];
    const int*   edge_v   = (const int*)d_in[3];
    const float* W_in1 = (const float*)d_in[6];
    const float* b_in1 = (const float*)d_in[7];
    const float* W_in2 = (const float*)d_in[8];
    const float* b_in2 = (const float*)d_in[9];
    const float* W_emb = (const float*)d_in[10];
    const float* b_emb = (const float*)d_in[11];
    const float* rel_mats = (const float*)d_in[12];
    const float* W_ih = (const float*)d_in[13];
    const float* W_hh = (const float*)d_in[14];
    const float* b_ih = (const float*)d_in[15];
    const float* b_hh = (const float*)d_in[16];
    const float* W_o1 = (const float*)d_in[17];
    const float* b_o1 = (const float*)d_in[18];
    const float* W_o2 = (const float*)d_in[19];
    const float* b_o2 = (const float*)d_in[20];
    float* out = (float*)d_out;

    char* ws = (char*)d_ws;
    size_t off = 0;
    auto alloc = [&](size_t bytes) -> void* {
        void* p = ws + off;
        off = (off + bytes + 255) & ~(size_t)255;
        return p;
    };
    int* segcnt    = (int*)alloc((size_t)T * N * SEG * 4);
    int* segoff    = (int*)alloc((size_t)T * N * SEG * 4);
    int* counts    = (int*)alloc(2048 * 4);
    int* ptr       = (int*)alloc(2048 * 4);
    int* sv        = (int*)alloc((size_t)T * E * 4);
    float* inorm   = (float*)alloc((size_t)NDIM * 4);
    float* Ab      = (float*)alloc((size_t)B * H1 * 4);
    float* W1T     = (float*)alloc((size_t)WVD * H1 * 4);
    float* Wvb     = (float*)alloc((size_t)N * H1 * 4);
    float* embs    = (float*)alloc((size_t)N * EMB * 4);
    float* Ahat    = (float*)alloc((size_t)T * N * RC * 4);   // per-type buffers
    float* wbuf    = (float*)alloc((size_t)T * E * 64 * 4);
    float* h0      = (float*)alloc((size_t)B * NDIM * 4);
    float* sT      = (float*)alloc((size_t)(STEPS + 1) * NDIM * B * 4);
    unsigned* bar  = (unsigned*)alloc(256);

    k_f1<<<F1_TOT, 256, 0, stream>>>(edge_u, segcnt, inputs, W_in1, Ab, W1T,
                                     wordvecs, W_emb, b_emb, embs);
    k_f2<<<F2_TOT, 256, 0, stream>>>(segcnt, segoff, counts, ptr,
                                     wordvecs, W1T, Wvb, embs, rel_mats, Ahat);
    k_f3<<<F3_TOT, 256, 0, stream>>>(edge_u, edge_v, ptr, segoff, sv,
                                     Ab, Wvb, b_in1, W_in2, b_in2, h0);
    k_f4<<<F4_TOT, 256, 0, stream>>>(ptr, counts, sv, embs, Ahat, wbuf, h0, sT);
    k_norm<<<N / 4, 256, 0, stream>>>(ptr, counts, wbuf, inorm, bar);
    k_steps<<<NBLK_STEPS, 256, 0, stream>>>(ptr, counts, sv, wbuf, inorm, sT,
                                            W_ih, W_hh, b_ih, b_hh,
                                            W_o1, b_o1, W_o2, b_o2, out, bar);
}

// Round 6
// 321.124 us; speedup vs baseline: 2.1929x; 2.1929x over previous
//
#include <hip/hip_runtime.h>
#include <math.h>

constexpr int B = 32, N = 1024, ND = 8, FEAT = 2048, WVD = 300;
constexpr int E = 20000, T = 2, STEPS = 5;
constexpr int NDIM = N * ND;            // 8192
constexpr int H1 = 512;
constexpr int W1C = FEAT + WVD;         // 2348
constexpr int EMB = 50;
constexpr int RC = EMB * ND * ND;       // 3200
constexpr int SEG = 16;
constexpr int SEGLEN = E / SEG;         // 1250 (NOT a multiple of 64 — guard!)
constexpr int GRP = 8;

// fused-kernel block ranges
constexpr int G_SEGH = T * N * SEG / 4;   // 8192
constexpr int G_A    = 128 * 32;          // 4096
constexpr int G_W1T  = 16 * 10;           // 160
constexpr int G_EMBS = 256;
constexpr int F1_TOT = G_SEGH + G_A + G_W1T + G_EMBS;

constexpr int G_WV2  = 256;               // (2 c-tiles) x (128 n-tiles)
constexpr int G_AHAT = 13 * 128 * 2;      // 3328
constexpr int F2_TOT = 1 + G_WV2 + G_AHAT;

constexpr int G_SCAT = T * N * SEG / 4;   // 8192
constexpr int G_INP  = B * N / 4;         // 8192
constexpr int F3_TOT = G_SCAT + G_INP;

// ============ F1: seghist | A | W1-transpose | embs (all independent) ============
__global__ __launch_bounds__(256) void k_f1(
        const int* eu, int* segcnt,
        const float* inp, const float* W1, float* Ab, float* W1T,
        const float* wv, const float* We, const float* be, float* embs) {
    __shared__ float smem[32 * 33];
    int tid = threadIdx.x;
    int blk = blockIdx.x;
    if (blk < G_SEGH) {
        int wid = blk * 4 + (tid >> 6);
        int lane = tid & 63;
        int t = wid >> 14, u = (wid >> 4) & (N - 1), seg = wid & (SEG - 1);
        const int* eut = eu + t * E;
        int e0 = seg * SEGLEN, e1 = e0 + SEGLEN, cnt = 0;
        for (int c = e0; c < e1; c += 64) {
            int e = c + lane;
            bool ok = (e < e1) && (eut[e] == u);
            cnt += __popcll(__ballot(ok));
        }
        if (lane == 0) segcnt[wid] = cnt;
    } else if (blk < G_SEGH + G_A) {
        int lb = blk - G_SEGH;
        int lane = tid & 63, w = tid >> 6;
        int c = (lb & 127) * 4 + w, b = lb >> 7;
        const float* xr = inp + (size_t)b * FEAT;
        const float* wr = W1 + (size_t)c * W1C;
        float acc = 0.f;
#pragma unroll
        for (int i = 0; i < FEAT / 64; i++) {
            int k = i * 64 + lane;
            acc += xr[k] * wr[k];
        }
        for (int m = 32; m; m >>= 1) acc += __shfl_xor(acc, m, 64);
        if (lane == 0) Ab[b * H1 + c] = acc;
    } else if (blk < G_SEGH + G_A + G_W1T) {
        int lb = blk - G_SEGH - G_A;
        int c0 = (lb % 16) * 32, k0 = (lb / 16) * 32;
        float (*tile)[33] = (float(*)[33])smem;
        int kl = tid & 31, cl4 = tid >> 5;
#pragma unroll
        for (int p = 0; p < 4; p++) {
            int c = cl4 + p * 8;
            int k = k0 + kl;
            if (k < WVD) tile[c][kl] = W1[(size_t)(c0 + c) * W1C + FEAT + k];
        }
        __syncthreads();
        int cl = tid & 31, kl4 = tid >> 5;
#pragma unroll
        for (int p = 0; p < 4; p++) {
            int kk = kl4 + p * 8;
            int k = k0 + kk;
            if (k < WVD) W1T[(size_t)k * H1 + c0 + cl] = tile[cl][kk];
        }
    } else {
        int lb = blk - G_SEGH - G_A - G_W1T;
        int i = lb * 256 + tid;
        int n = i >> 6, c = i & 63;
        if (c >= EMB) return;
        const float* xr = wv + (size_t)n * WVD;
        const float* wr = We + (size_t)c * WVD;
        float acc = be[c];
        for (int k = 0; k < WVD; k++) acc += xr[k] * wr[k];
        embs[n * EMB + c] = acc;
    }
}

// ============ F2: seg-scan+global-scan (1 block) | Wv GEMM | Ahat GEMM x2 ============
__global__ __launch_bounds__(256) void k_f2(
        const int* segcnt, int* segoff, int* counts, int* ptr,
        const float* wv, const float* W1T, float* Wvb,
        const float* embs, const float* RMbase, float* Ahat) {
    __shared__ float smemf[4096];   // 16 KB, aliased per role
    int tid = threadIdx.x, blk = blockIdx.x;
    if (blk == 0) {
        int* sc = (int*)smemf;      // [0..2047] + [2048..4095] ping-pong
        for (int row = tid; row < 2048; row += 256) {
            int acc = 0;
            const int* src = segcnt + row * SEG;
            int* dst = segoff + row * SEG;
#pragma unroll
            for (int s = 0; s < SEG; s++) { dst[s] = acc; acc += src[s]; }
            counts[row] = acc;
            sc[row] = acc;
        }
        __syncthreads();
        int* src = sc; int* dst = sc + 2048;
        for (int st = 1; st < 2048; st <<= 1) {
            for (int j = tid; j < 2048; j += 256)
                dst[j] = src[j] + (j >= st ? src[j - st] : 0);
            __syncthreads();
            int* tmp = src; src = dst; dst = tmp;
        }
        for (int j = tid; j < 2048; j += 256)
            ptr[j] = j ? src[j - 1] : 0;
    } else if (blk <= G_WV2) {
        int lb = blk - 1;
        int c = (lb & 1) * 256 + tid;
        int n0 = (lb >> 1) * 8;
        float (*el)[WVD] = (float(*)[WVD])smemf;
        for (int idx = tid; idx < 8 * WVD; idx += 256)
            el[idx / WVD][idx % WVD] = wv[(size_t)(n0 + idx / WVD) * WVD + idx % WVD];
        __syncthreads();
        float acc[8] = {};
        for (int k = 0; k < WVD; k++) {
            float r = W1T[(size_t)k * H1 + c];
#pragma unroll
            for (int j = 0; j < 8; j++) acc[j] += el[j][k] * r;
        }
#pragma unroll
        for (int j = 0; j < 8; j++) Wvb[(size_t)(n0 + j) * H1 + c] = acc[j];
    } else {
        int lb = blk - 1 - G_WV2;
        int t = lb / 1664, r = lb % 1664;
        int bx = r % 13, by = r / 13;
        const float* RM = RMbase + (size_t)t * EMB * RC;
        float* Ah = Ahat + (size_t)t * N * RC;
        float (*el)[EMB] = (float(*)[EMB])smemf;
        int n0 = by * 8;
        for (int i = tid; i < 8 * EMB; i += 256)
            el[i / EMB][i % EMB] = embs[(n0 + i / EMB) * EMB + i % EMB];
        __syncthreads();
        int m = bx * 256 + tid;
        if (m < RC) {
            float acc[8] = {};
            for (int c = 0; c < EMB; c++) {
                float rr = RM[(size_t)c * RC + m];
#pragma unroll
                for (int j = 0; j < 8; j++) acc[j] += el[j][c] * rr;
            }
#pragma unroll
            for (int j = 0; j < 8; j++) Ah[(size_t)(n0 + j) * RC + m] = acc[j];
        }
    }
}

// ============ F3: scatter | inputnet (writes sT[0] directly, transposed) ============
__global__ __launch_bounds__(256) void k_f3(
        const int* eu, const int* ev, const int* ptr, const int* segoff, int* sv,
        const float* Ab, const float* Wvb, const float* b1,
        const float* W2, const float* b2, float* sT0) {
    int tid = threadIdx.x, blk = blockIdx.x;
    if (blk < G_SCAT) {
        int wid = blk * 4 + (tid >> 6);
        int lane = tid & 63;
        int t = wid >> 14, u = (wid >> 4) & (N - 1), seg = wid & (SEG - 1);
        const int* eut = eu + t * E;
        const int* evt = ev + t * E;
        int row = t * N + u;
        int base = ptr[row] + segoff[row * SEG + seg];
        int e0 = seg * SEGLEN, e1 = e0 + SEGLEN, cnt = 0;
        for (int c = e0; c < e1; c += 64) {
            int e = c + lane;
            bool ok = (e < e1) && (eut[e] == u);
            unsigned long long m = __ballot(ok);
            if (ok) {
                int rank = __popcll(m & ((1ull << lane) - 1));
                sv[base + cnt + rank] = evt[e];
            }
            cnt += __popcll(m);
        }
    } else {
        int lb = blk - G_SCAT;
        int gw = lb * 4 + (tid >> 6);
        int lane = tid & 63;
        int b = gw >> 10, n = gw & (N - 1);
        const float* ar = Ab + b * H1;
        const float* vr = Wvb + n * H1;
        float acc[8] = {};
#pragma unroll
        for (int i = 0; i < H1 / 64; i++) {
            int c = i * 64 + lane;
            float t = ar[c] + vr[c] + b1[c];
            t = fmaxf(t, 0.f);
#pragma unroll
            for (int ki = 0; ki < 8; ki++) acc[ki] += t * W2[ki * H1 + c];
        }
#pragma unroll
        for (int ki = 0; ki < 8; ki++)
            for (int m = 32; m; m >>= 1) acc[ki] += __shfl_xor(acc[ki], m, 64);
        // after butterfly every lane holds the full sums; lanes 0..7 scatter
        float myv = 0.f;
#pragma unroll
        for (int ki = 0; ki < 8; ki++)
            if (lane == ki) myv = acc[ki] + b2[ki];
        if (lane < 8)
            sT0[((size_t)n * 8 + lane) * B + b] = myv;
    }
}

// ============ F4: edge weights for BOTH types per u + fused row norms ============
__global__ __launch_bounds__(256) void k_f4(
        const int* ptr, const int* counts, const int* sv,
        const float* embs, const float* Ahat, float* wbuf, float* inorm) {
    __shared__ float AL[RC];   // 12.8 KB; reused as 4x64 reduce buffer at the end
    int tid = threadIdx.x;
    int u = blockIdx.x;
    int wv_ = tid >> 6, k = tid & 63;
    float ssq = 0.f;
    for (int t = 0; t < T; t++) {
        __syncthreads();   // protect AL from previous type's readers
        for (int idx = tid; idx < RC; idx += 256)
            AL[idx] = Ahat[((size_t)t * N + u) * RC + idx];
        __syncthreads();
        int base = ptr[t * N + u], cnt = counts[t * N + u];
        for (int i = wv_; i < cnt; i += 4) {
            int slot = base + i;
            int v = sv[slot];
            const float* vr = embs + v * EMB;
            float acc = 0.f;
#pragma unroll 10
            for (int d = 0; d < EMB; d++) acc += vr[d] * AL[d * 64 + k];
            wbuf[(size_t)slot * 64 + k] = acc;
            ssq += acc * acc;
        }
    }
    __syncthreads();
    AL[wv_ * 64 + k] = ssq;
    __syncthreads();
    if (tid < 64) {
        float tot = AL[tid] + AL[64 + tid] + AL[128 + tid] + AL[192 + tid];
        tot += __shfl_xor(tot, 1, 64);
        tot += __shfl_xor(tot, 2, 64);
        tot += __shfl_xor(tot, 4, 64);
        int ki = tid >> 3, kj = tid & 7;
        if (kj == 0) {
            float nv = sqrtf(tot);
            if (nv == 0.f) nv = 1.f;
            inorm[u * ND + ki] = 1.0f / nv;
        }
    }
}

// ============ propagation step (per-launch); last launch fuses outnet ============
__global__ __launch_bounds__(256) void k_step(
        const int* ptr, const int* counts, const int* sv,
        const float* wbuf, const float* inorm, const float* sT, int s,
        const float* W_ih, const float* W_hh, const float* b_ih, const float* b_hh,
        const float* Wo1, const float* bo1, const float* Wo2, const float* bo2,
        float* sOut, float* out, int last) {
    __shared__ float wl[GRP][64];
    __shared__ float hvl[GRP][8][32];
    __shared__ float wih[192], whh[192];
    __shared__ float w1s[160], b1s[20], w2s[20];
    __shared__ float res[8][33];
    int tid = threadIdx.x;
    int u = blockIdx.x;
    int ki = tid >> 5, b = tid & 31;
    if (tid < 192) { wih[tid] = W_ih[tid]; whh[tid] = W_hh[tid]; }
    if (last) {
        if (tid < 160) w1s[tid] = Wo1[tid];
        if (tid < 20) { b1s[tid] = bo1[tid]; w2s[tid] = Wo2[tid]; }
    }
    const float* sIn = sT + (size_t)s * NDIM * B;
    float hown = sIn[((size_t)u * 8 + ki) * B + b];
    float acc = 0.f;
    for (int t = 0; t < T; t++) {
        int base = ptr[t * N + u], cnt = counts[t * N + u];
        for (int c0 = 0; c0 < cnt; c0 += GRP) {
            int nb = min(GRP, cnt - c0);
            __syncthreads();
#pragma unroll
            for (int r = 0; r < 2; r++) {
                int idx = tid + r * 256;
                int e = idx >> 6, k = idx & 63;
                float w = 0.f;
                if (e < nb) {
                    int v = sv[base + c0 + e];
                    w = wbuf[(size_t)(base + c0 + e) * 64 + k]
                        * inorm[v * ND + (k & 7)];
                }
                wl[e][k] = w;
            }
#pragma unroll
            for (int j = 0; j < GRP; j++) {
                int vj = (j < nb) ? sv[base + c0 + j] : 0;
                hvl[j][ki][b] = sIn[((size_t)vj * 8 + ki) * B + b];
            }
            __syncthreads();
#pragma unroll
            for (int j = 0; j < GRP; j++) {
                const float* wj = &wl[j][ki * 8];
                const float* hj = &hvl[j][0][b];
#pragma unroll
                for (int kj = 0; kj < 8; kj++)
                    acc += wj[kj] * hj[kj * 32];
            }
        }
    }
    float xv = tanhf(acc);
    __syncthreads();
    float* xs = &hvl[0][0][0];
    float* hs = &hvl[2][0][0];
    xs[ki * 32 + b] = xv;
    hs[ki * 32 + b] = hown;
    __syncthreads();
    float gr = b_ih[ki], gz = b_ih[8 + ki], gn = b_ih[16 + ki];
    float hr = b_hh[ki], hz = b_hh[8 + ki], hn = b_hh[16 + ki];
#pragma unroll
    for (int j = 0; j < 8; j++) {
        float xj = xs[j * 32 + b], hj = hs[j * 32 + b];
        gr += wih[ki * 8 + j] * xj;
        gz += wih[(8 + ki) * 8 + j] * xj;
        gn += wih[(16 + ki) * 8 + j] * xj;
        hr += whh[ki * 8 + j] * hj;
        hz += whh[(8 + ki) * 8 + j] * hj;
        hn += whh[(16 + ki) * 8 + j] * hj;
    }
    float r = 1.f / (1.f + expf(-(gr + hr)));
    float z = 1.f / (1.f + expf(-(gz + hz)));
    float nn = tanhf(gn + r * hn);
    float hnew = (1.f - z) * nn + z * hown;
    if (!last) {
        sOut[((size_t)u * 8 + ki) * B + b] = hnew;
        return;
    }
    // ---- fused outnet: s=STEPS state lives only in LDS ----
    __syncthreads();
    float* hfin = &wl[0][0];           // 256 floats
    hfin[ki * 32 + b] = hnew;
    __syncthreads();
    int s6 = tid >> 5, bb = tid & 31;
    if (s6 < 6) {
        float x[8];
#pragma unroll
        for (int kk = 0; kk < 8; kk++)
            x[kk] = (s6 < STEPS)
                ? sT[((size_t)s6 * NDIM + u * 8 + kk) * B + bb]
                : hfin[kk * 32 + bb];
        float accv = bo2[0];
#pragma unroll
        for (int j = 0; j < 20; j++) {
            float h = b1s[j];
#pragma unroll
            for (int kk = 0; kk < 8; kk++) h += w1s[j * 8 + kk] * x[kk];
            h = fmaxf(h, 0.f);
            accv += w2s[j] * h;
        }
        res[s6][bb] = accv;
    }
    __syncthreads();
    if (tid < 192) {
        int b_w = tid / 6, s_w = tid - b_w * 6;
        out[(size_t)b_w * ((STEPS + 1) * N) + u * (STEPS + 1) + s_w] = res[s_w][b_w];
    }
}

extern "C" void kernel_launch(void* const* d_in, const int* in_sizes, int n_in,
                              void* d_out, int out_size, void* d_ws, size_t ws_size,
                              hipStream_t stream) {
    const float* inputs   = (const float*)d_in[0];
    const float* wordvecs = (const float*)d_in[1];
    const int*   edge_u   = (const int*)d_in[2];
    const int*   edge_v   = (const int*)d_in[3];
    const float* W_in1 = (const float*)d_in[6];
    const float* b_in1 = (const float*)d_in[7];
    const float* W_in2 = (const float*)d_in[8];
    const float* b_in2 = (const float*)d_in[9];
    const float* W_emb = (const float*)d_in[10];
    const float* b_emb = (const float*)d_in[11];
    const float* rel_mats = (const float*)d_in[12];
    const float* W_ih = (const float*)d_in[13];
    const float* W_hh = (const float*)d_in[14];
    const float* b_ih = (const float*)d_in[15];
    const float* b_hh = (const float*)d_in[16];
    const float* W_o1 = (const float*)d_in[17];
    const float* b_o1 = (const float*)d_in[18];
    const float* W_o2 = (const float*)d_in[19];
    const float* b_o2 = (const float*)d_in[20];
    float* out = (float*)d_out;

    char* ws = (char*)d_ws;
    size_t off = 0;
    auto alloc = [&](size_t bytes) -> void* {
        void* p = ws + off;
        off = (off + bytes + 255) & ~(size_t)255;
        return p;
    };
    int* segcnt    = (int*)alloc((size_t)T * N * SEG * 4);
    int* segoff    = (int*)alloc((size_t)T * N * SEG * 4);
    int* counts    = (int*)alloc(2048 * 4);
    int* ptr       = (int*)alloc(2048 * 4);
    int* sv        = (int*)alloc((size_t)T * E * 4);
    float* inorm   = (float*)alloc((size_t)NDIM * 4);
    float* Ab      = (float*)alloc((size_t)B * H1 * 4);
    float* W1T     = (float*)alloc((size_t)WVD * H1 * 4);
    float* Wvb     = (float*)alloc((size_t)N * H1 * 4);
    float* embs    = (float*)alloc((size_t)N * EMB * 4);
    float* Ahat    = (float*)alloc((size_t)T * N * RC * 4);
    float* wbuf    = (float*)alloc((size_t)T * E * 64 * 4);
    float* sT      = (float*)alloc((size_t)(STEPS + 1) * NDIM * B * 4);

    k_f1<<<F1_TOT, 256, 0, stream>>>(edge_u, segcnt, inputs, W_in1, Ab, W1T,
                                     wordvecs, W_emb, b_emb, embs);
    k_f2<<<F2_TOT, 256, 0, stream>>>(segcnt, segoff, counts, ptr,
                                     wordvecs, W1T, Wvb, embs, rel_mats, Ahat);
    k_f3<<<F3_TOT, 256, 0, stream>>>(edge_u, edge_v, ptr, segoff, sv,
                                     Ab, Wvb, b_in1, W_in2, b_in2, sT);
    k_f4<<<N, 256, 0, stream>>>(ptr, counts, sv, embs, Ahat, wbuf, inorm);

    for (int s = 0; s < STEPS; s++) {
        int last = (s == STEPS - 1) ? 1 : 0;
        k_step<<<N, 256, 0, stream>>>(ptr, counts, sv, wbuf, inorm, sT, s,
                                      W_ih, W_hh, b_ih, b_hh,
                                      W_o1, b_o1, W_o2, b_o2,
                                      sT + (size_t)(s + 1) * NDIM * B, out, last);
    }
}

// Round 7
// 299.402 us; speedup vs baseline: 2.3520x; 1.0726x over previous
//
#include <hip/hip_runtime.h>
#include <math.h>

constexpr int B = 32, N = 1024, ND = 8, FEAT = 2048, WVD = 300;
constexpr int E = 20000, T = 2, STEPS = 5;
constexpr int NDIM = N * ND;            // 8192
constexpr int H1 = 512;
constexpr int W1C = FEAT + WVD;         // 2348
constexpr int EMB = 50;
constexpr int RC = EMB * ND * ND;       // 3200
constexpr int SEG = 16;
constexpr int SEGLEN = E / SEG;         // 1250 (NOT a multiple of 64 — guard!)

// fused-kernel block ranges
constexpr int G_SEGH = T * N * SEG / 4;   // 8192
constexpr int G_A    = 128 * 32;          // 4096
constexpr int G_W1T  = 16 * 10;           // 160
constexpr int G_EMBS = 256;
constexpr int F1_TOT = G_SEGH + G_A + G_W1T + G_EMBS;

constexpr int G_WV2  = 256;               // (2 c-tiles) x (128 n-tiles)
constexpr int G_AHAT = 13 * 128 * 2;      // 3328
constexpr int F2_TOT = 1 + G_WV2 + G_AHAT;

constexpr int F4_TOT = 2 * N;             // weights(1024) + inputnet(1024)

// ============ F1: seghist | A (writes AbT) | W1-transpose | embs ============
__global__ __launch_bounds__(256) void k_f1(
        const int* eu, int* segcnt,
        const float* inp, const float* W1, float* AbT, float* W1T,
        const float* wv, const float* We, const float* be, float* embs) {
    __shared__ float smem[32 * 33];
    int tid = threadIdx.x;
    int blk = blockIdx.x;
    if (blk < G_SEGH) {
        int wid = blk * 4 + (tid >> 6);
        int lane = tid & 63;
        int t = wid >> 14, u = (wid >> 4) & (N - 1), seg = wid & (SEG - 1);
        const int* eut = eu + t * E;
        int e0 = seg * SEGLEN, e1 = e0 + SEGLEN, cnt = 0;
        for (int c = e0; c < e1; c += 64) {
            int e = c + lane;
            bool ok = (e < e1) && (eut[e] == u);
            cnt += __popcll(__ballot(ok));
        }
        if (lane == 0) segcnt[wid] = cnt;
    } else if (blk < G_SEGH + G_A) {
        int lb = blk - G_SEGH;
        int lane = tid & 63, w = tid >> 6;
        int c = (lb & 127) * 4 + w, b = lb >> 7;
        const float* xr = inp + (size_t)b * FEAT;
        const float* wr = W1 + (size_t)c * W1C;
        float acc = 0.f;
#pragma unroll
        for (int i = 0; i < FEAT / 64; i++) {
            int k = i * 64 + lane;
            acc += xr[k] * wr[k];
        }
        for (int m = 32; m; m >>= 1) acc += __shfl_xor(acc, m, 64);
        if (lane == 0) AbT[c * B + b] = acc;       // transposed store
    } else if (blk < G_SEGH + G_A + G_W1T) {
        int lb = blk - G_SEGH - G_A;
        int c0 = (lb % 16) * 32, k0 = (lb / 16) * 32;
        float (*tile)[33] = (float(*)[33])smem;
        int kl = tid & 31, cl4 = tid >> 5;
#pragma unroll
        for (int p = 0; p < 4; p++) {
            int c = cl4 + p * 8;
            int k = k0 + kl;
            if (k < WVD) tile[c][kl] = W1[(size_t)(c0 + c) * W1C + FEAT + k];
        }
        __syncthreads();
        int cl = tid & 31, kl4 = tid >> 5;
#pragma unroll
        for (int p = 0; p < 4; p++) {
            int kk = kl4 + p * 8;
            int k = k0 + kk;
            if (k < WVD) W1T[(size_t)k * H1 + c0 + cl] = tile[cl][kk];
        }
    } else {
        int lb = blk - G_SEGH - G_A - G_W1T;
        int i = lb * 256 + tid;
        int n = i >> 6, c = i & 63;
        if (c >= EMB) return;
        const float* xr = wv + (size_t)n * WVD;
        const float* wr = We + (size_t)c * WVD;
        float acc = be[c];
        for (int k = 0; k < WVD; k++) acc += xr[k] * wr[k];
        embs[n * EMB + c] = acc;
    }
}

// ============ F2: seg-scan+global-scan (1 block) | Wv GEMM | Ahat GEMM x2 ============
__global__ __launch_bounds__(256) void k_f2(
        const int* segcnt, int* segoff, int* counts, int* ptr,
        const float* wv, const float* W1T, float* Wvb,
        const float* embs, const float* RMbase, float* Ahat) {
    __shared__ float smemf[4096];   // 16 KB, aliased per role
    int tid = threadIdx.x, blk = blockIdx.x;
    if (blk == 0) {
        int* sc = (int*)smemf;
        for (int row = tid; row < 2048; row += 256) {
            int acc = 0;
            const int* src = segcnt + row * SEG;
            int* dst = segoff + row * SEG;
#pragma unroll
            for (int s = 0; s < SEG; s++) { dst[s] = acc; acc += src[s]; }
            counts[row] = acc;
            sc[row] = acc;
        }
        __syncthreads();
        int* src = sc; int* dst = sc + 2048;
        for (int st = 1; st < 2048; st <<= 1) {
            for (int j = tid; j < 2048; j += 256)
                dst[j] = src[j] + (j >= st ? src[j - st] : 0);
            __syncthreads();
            int* tmp = src; src = dst; dst = tmp;
        }
        for (int j = tid; j < 2048; j += 256)
            ptr[j] = j ? src[j - 1] : 0;
    } else if (blk <= G_WV2) {
        int lb = blk - 1;
        int c = (lb & 1) * 256 + tid;
        int n0 = (lb >> 1) * 8;
        float (*el)[WVD] = (float(*)[WVD])smemf;
        for (int idx = tid; idx < 8 * WVD; idx += 256)
            el[idx / WVD][idx % WVD] = wv[(size_t)(n0 + idx / WVD) * WVD + idx % WVD];
        __syncthreads();
        float acc[8] = {};
        for (int k = 0; k < WVD; k++) {
            float r = W1T[(size_t)k * H1 + c];
#pragma unroll
            for (int j = 0; j < 8; j++) acc[j] += el[j][k] * r;
        }
#pragma unroll
        for (int j = 0; j < 8; j++) Wvb[(size_t)(n0 + j) * H1 + c] = acc[j];
    } else {
        int lb = blk - 1 - G_WV2;
        int t = lb / 1664, r = lb % 1664;
        int bx = r % 13, by = r / 13;
        const float* RM = RMbase + (size_t)t * EMB * RC;
        float* Ah = Ahat + (size_t)t * N * RC;
        float (*el)[EMB] = (float(*)[EMB])smemf;
        int n0 = by * 8;
        for (int i = tid; i < 8 * EMB; i += 256)
            el[i / EMB][i % EMB] = embs[(n0 + i / EMB) * EMB + i % EMB];
        __syncthreads();
        int m = bx * 256 + tid;
        if (m < RC) {
            float acc[8] = {};
            for (int c = 0; c < EMB; c++) {
                float rr = RM[(size_t)c * RC + m];
#pragma unroll
                for (int j = 0; j < 8; j++) acc[j] += el[j][c] * rr;
            }
#pragma unroll
            for (int j = 0; j < 8; j++) Ah[(size_t)(n0 + j) * RC + m] = acc[j];
        }
    }
}

// ============ F3: scatter only (zero LDS, full occupancy) ============
__global__ __launch_bounds__(256) void k_f3(
        const int* eu, const int* ev, const int* ptr, const int* segoff, int* sv) {
    int tid = threadIdx.x, blk = blockIdx.x;
    int wid = blk * 4 + (tid >> 6);
    int lane = tid & 63;
    int t = wid >> 14, u = (wid >> 4) & (N - 1), seg = wid & (SEG - 1);
    const int* eut = eu + t * E;
    const int* evt = ev + t * E;
    int row = t * N + u;
    int base = ptr[row] + segoff[row * SEG + seg];
    int e0 = seg * SEGLEN, e1 = e0 + SEGLEN, cnt = 0;
    for (int c = e0; c < e1; c += 64) {
        int e = c + lane;
        bool ok = (e < e1) && (eut[e] == u);
        unsigned long long m = __ballot(ok);
        if (ok) {
            int rank = __popcll(m & ((1ull << lane) - 1));
            sv[base + cnt + rank] = evt[e];
        }
        cnt += __popcll(m);
    }
}

// ============ F4: edge weights + norms (blocks 0..N-1) | inputnet (blocks N..2N-1) ============
__global__ __launch_bounds__(256) void k_f4(
        const int* ptr, const int* counts, const int* sv,
        const float* embs, const float* Ahat, float* wbuf, float* inorm,
        const float* AbT, const float* Wvb, const float* b1,
        const float* W2, const float* b2, float* sT0) {
    __shared__ float smem[6656];   // 26 KB: weights use [0..3199]; inputnet partitions below
    int tid = threadIdx.x;
    int blk = blockIdx.x;
    if (blk < N) {
        // -------- edge weights for both types + fused row norms --------
        float* AL = smem;
        int u = blk;
        int wv_ = tid >> 6, k = tid & 63;
        float ssq = 0.f;
        for (int t = 0; t < T; t++) {
            __syncthreads();
            for (int idx = tid; idx < RC; idx += 256)
                AL[idx] = Ahat[((size_t)t * N + u) * RC + idx];
            __syncthreads();
            int base = ptr[t * N + u], cnt = counts[t * N + u];
            for (int i = wv_; i < cnt; i += 4) {
                int slot = base + i;
                int v = sv[slot];
                const float* vr = embs + v * EMB;
                float acc = 0.f;
#pragma unroll 10
                for (int d = 0; d < EMB; d++) acc += vr[d] * AL[d * 64 + k];
                wbuf[(size_t)slot * 64 + k] = acc;
                ssq += acc * acc;
            }
        }
        __syncthreads();
        AL[wv_ * 64 + k] = ssq;
        __syncthreads();
        if (tid < 64) {
            float tot = AL[tid] + AL[64 + tid] + AL[128 + tid] + AL[192 + tid];
            tot += __shfl_xor(tot, 1, 64);
            tot += __shfl_xor(tot, 2, 64);
            tot += __shfl_xor(tot, 4, 64);
            int ki = tid >> 3, kj = tid & 7;
            if (kj == 0) {
                float nv = sqrtf(tot);
                if (nv == 0.f) nv = 1.f;
                inorm[u * ND + ki] = 1.0f / nv;
            }
        }
    } else {
        // -------- inputnet: block per n, W2+Wv staged in LDS --------
        int n = blk - N;
        float* w2s  = smem;            // 4096
        float* wvs  = smem + 4096;     // 512
        float* part = smem + 4608;     // 2048
        for (int idx = tid; idx < 8 * H1; idx += 256) w2s[idx] = W2[idx];
        for (int idx = tid; idx < H1; idx += 256)
            wvs[idx] = Wvb[(size_t)n * H1 + idx] + b1[idx];
        __syncthreads();
        int b = tid & 31, s = tid >> 5;
        float acc[8] = {};
        for (int i = 0; i < 64; i++) {
            int c = s * 64 + i;
            float tv = fmaxf(AbT[c * 32 + b] + wvs[c], 0.f);
#pragma unroll
            for (int ki = 0; ki < 8; ki++) acc[ki] += tv * w2s[ki * H1 + c];
        }
#pragma unroll
        for (int ki = 0; ki < 8; ki++) part[s * 256 + ki * 32 + b] = acc[ki];
        __syncthreads();
        int ki2 = tid >> 5, b2i = tid & 31;
        float tot = b2[ki2];
#pragma unroll
        for (int s2 = 0; s2 < 8; s2++) tot += part[s2 * 256 + ki2 * 32 + b2i];
        sT0[(size_t)n * 256 + tid] = tot;   // = sT0[(n*8+ki)*B + b]
    }
}

// ============ propagation step: barrier-free SpMM + GRU; last fuses outnet ============
__global__ __launch_bounds__(256) void k_step(
        const int* ptr, const int* counts, const int* sv,
        const float* wbuf, const float* inorm, const float* sT, int s,
        const float* W_ih, const float* W_hh, const float* b_ih, const float* b_hh,
        const float* Wo1, const float* bo1, const float* Wo2, const float* bo2,
        float* sOut, float* out, int last) {
    __shared__ float xs[256], hs[256], hfin[256];
    __shared__ float wih[192], whh[192];
    __shared__ float w1s[160], b1s[20], w2s[20];
    __shared__ float res[8][33];
    int tid = threadIdx.x;
    int u = blockIdx.x;
    int ki = tid >> 5, b = tid & 31;
    if (tid < 192) { wih[tid] = W_ih[tid]; whh[tid] = W_hh[tid]; }
    if (last) {
        if (tid < 160) w1s[tid] = Wo1[tid];
        if (tid < 20) { b1s[tid] = bo1[tid]; w2s[tid] = Wo2[tid]; }
    }
    const float* sIn = sT + (size_t)s * NDIM * B;
    float hown = sIn[((size_t)u * 8 + ki) * B + b];
    float acc = 0.f;
    for (int t = 0; t < T; t++) {
        int base = ptr[t * N + u], cnt = counts[t * N + u];
        for (int i = 0; i < cnt; i++) {
            int slot = base + i;
            int v = sv[slot];                      // block-uniform -> s_load
            const float* wp = wbuf + (size_t)slot * 64 + ki * 8;
            float4 wa = *(const float4*)wp;
            float4 wb = *(const float4*)(wp + 4);
            const float* ip = inorm + v * ND;      // uniform -> s_loads
            const float* hp = sIn + (size_t)v * 256 + b;
            acc += (wa.x * ip[0]) * hp[0]
                 + (wa.y * ip[1]) * hp[32]
                 + (wa.z * ip[2]) * hp[64]
                 + (wa.w * ip[3]) * hp[96]
                 + (wb.x * ip[4]) * hp[128]
                 + (wb.y * ip[5]) * hp[160]
                 + (wb.z * ip[6]) * hp[192]
                 + (wb.w * ip[7]) * hp[224];
        }
    }
    float xv = tanhf(acc);
    xs[ki * 32 + b] = xv;
    hs[ki * 32 + b] = hown;
    __syncthreads();
    float gr = b_ih[ki], gz = b_ih[8 + ki], gn = b_ih[16 + ki];
    float hr = b_hh[ki], hz = b_hh[8 + ki], hn = b_hh[16 + ki];
#pragma unroll
    for (int j = 0; j < 8; j++) {
        float xj = xs[j * 32 + b], hj = hs[j * 32 + b];
        gr += wih[ki * 8 + j] * xj;
        gz += wih[(8 + ki) * 8 + j] * xj;
        gn += wih[(16 + ki) * 8 + j] * xj;
        hr += whh[ki * 8 + j] * hj;
        hz += whh[(8 + ki) * 8 + j] * hj;
        hn += whh[(16 + ki) * 8 + j] * hj;
    }
    float r = 1.f / (1.f + expf(-(gr + hr)));
    float z = 1.f / (1.f + expf(-(gz + hz)));
    float nn = tanhf(gn + r * hn);
    float hnew = (1.f - z) * nn + z * hown;
    if (!last) {
        sOut[((size_t)u * 8 + ki) * B + b] = hnew;
        return;
    }
    // ---- fused outnet: s=STEPS state lives only in LDS ----
    hfin[ki * 32 + b] = hnew;
    __syncthreads();
    int s6 = tid >> 5, bb = tid & 31;
    if (s6 < 6) {
        float x[8];
#pragma unroll
        for (int kk = 0; kk < 8; kk++)
            x[kk] = (s6 < STEPS)
                ? sT[((size_t)s6 * NDIM + u * 8 + kk) * B + bb]
                : hfin[kk * 32 + bb];
        float accv = bo2[0];
#pragma unroll
        for (int j = 0; j < 20; j++) {
            float h = b1s[j];
#pragma unroll
            for (int kk = 0; kk < 8; kk++) h += w1s[j * 8 + kk] * x[kk];
            h = fmaxf(h, 0.f);
            accv += w2s[j] * h;
        }
        res[s6][bb] = accv;
    }
    __syncthreads();
    if (tid < 192) {
        int b_w = tid / 6, s_w = tid - b_w * 6;
        out[(size_t)b_w * ((STEPS + 1) * N) + u * (STEPS + 1) + s_w] = res[s_w][b_w];
    }
}

extern "C" void kernel_launch(void* const* d_in, const int* in_sizes, int n_in,
                              void* d_out, int out_size, void* d_ws, size_t ws_size,
                              hipStream_t stream) {
    const float* inputs   = (const float*)d_in[0];
    const float* wordvecs = (const float*)d_in[1];
    const int*   edge_u   = (const int*)d_in[2];
    const int*   edge_v   = (const int*)d_in[3];
    const float* W_in1 = (const float*)d_in[6];
    const float* b_in1 = (const float*)d_in[7];
    const float* W_in2 = (const float*)d_in[8];
    const float* b_in2 = (const float*)d_in[9];
    const float* W_emb = (const float*)d_in[10];
    const float* b_emb = (const float*)d_in[11];
    const float* rel_mats = (const float*)d_in[12];
    const float* W_ih = (const float*)d_in[13];
    const float* W_hh = (const float*)d_in[14];
    const float* b_ih = (const float*)d_in[15];
    const float* b_hh = (const float*)d_in[16];
    const float* W_o1 = (const float*)d_in[17];
    const float* b_o1 = (const float*)d_in[18];
    const float* W_o2 = (const float*)d_in[19];
    const float* b_o2 = (const float*)d_in[20];
    float* out = (float*)d_out;

    char* ws = (char*)d_ws;
    size_t off = 0;
    auto alloc = [&](size_t bytes) -> void* {
        void* p = ws + off;
        off = (off + bytes + 255) & ~(size_t)255;
        return p;
    };
    int* segcnt    = (int*)alloc((size_t)T * N * SEG * 4);
    int* segoff    = (int*)alloc((size_t)T * N * SEG * 4);
    int* counts    = (int*)alloc(2048 * 4);
    int* ptr       = (int*)alloc(2048 * 4);
    int* sv        = (int*)alloc((size_t)T * E * 4);
    float* inorm   = (float*)alloc((size_t)NDIM * 4);
    float* AbT     = (float*)alloc((size_t)H1 * B * 4);
    float* W1T     = (float*)alloc((size_t)WVD * H1 * 4);
    float* Wvb     = (float*)alloc((size_t)N * H1 * 4);
    float* embs    = (float*)alloc((size_t)N * EMB * 4);
    float* Ahat    = (float*)alloc((size_t)T * N * RC * 4);
    float* wbuf    = (float*)alloc((size_t)T * E * 64 * 4);
    float* sT      = (float*)alloc((size_t)(STEPS + 1) * NDIM * B * 4);

    k_f1<<<F1_TOT, 256, 0, stream>>>(edge_u, segcnt, inputs, W_in1, AbT, W1T,
                                     wordvecs, W_emb, b_emb, embs);
    k_f2<<<F2_TOT, 256, 0, stream>>>(segcnt, segoff, counts, ptr,
                                     wordvecs, W1T, Wvb, embs, rel_mats, Ahat);
    k_f3<<<T * N * SEG / 4, 256, 0, stream>>>(edge_u, edge_v, ptr, segoff, sv);
    k_f4<<<F4_TOT, 256, 0, stream>>>(ptr, counts, sv, embs, Ahat, wbuf, inorm,
                                     AbT, Wvb, b_in1, W_in2, b_in2, sT);

    for (int s = 0; s < STEPS; s++) {
        int last = (s == STEPS - 1) ? 1 : 0;
        k_step<<<N, 256, 0, stream>>>(ptr, counts, sv, wbuf, inorm, sT, s,
                                      W_ih, W_hh, b_ih, b_hh,
                                      W_o1, b_o1, W_o2, b_o2,
                                      sT + (size_t)(s + 1) * NDIM * B, out, last);
    }
}

// Round 8
// 276.433 us; speedup vs baseline: 2.5474x; 1.0831x over previous
//
#include <hip/hip_runtime.h>
#include <math.h>

constexpr int B = 32, N = 1024, ND = 8, FEAT = 2048, WVD = 300;
constexpr int E = 20000, T = 2, STEPS = 5;
constexpr int NDIM = N * ND;            // 8192
constexpr int H1 = 512;
constexpr int W1C = FEAT + WVD;         // 2348
constexpr int EMB = 50;
constexpr int RC = EMB * ND * ND;       // 3200
constexpr int SEG = 16;
constexpr int SEGLEN = E / SEG;         // 1250 (NOT a multiple of 64 — guard!)

// fused-kernel block ranges (k_f1): heavy-per-block sections first
constexpr int G_KA   = 64;                 // tiled inputs@W1 GEMM -> AbT
constexpr int G_W1T  = 16 * 10;            // W1 tail transpose
constexpr int G_EMB  = N * EMB / 4;        // 12800: wave per (n,c)
constexpr int G_SEGH = T * N * SEG / 4;    // 8192
constexpr int F1_TOT = G_KA + G_W1T + G_EMB + G_SEGH;

constexpr int G_WV2  = 256;                // (2 c-tiles) x (128 n-tiles)
constexpr int G_AHAT = 13 * (N / 32) * T;  // 832 (32 nodes per block)
constexpr int F2_TOT = 1 + G_WV2 + G_AHAT;

constexpr int F4_TOT = 2 * N;              // weights(1024) + inputnet(1024)

// ============ F1: k_A GEMM | W1-transpose | embs | seghist ============
__global__ __launch_bounds__(256) void k_f1(
        const int* eu, int* segcnt,
        const float* inp, const float* W1, float* AbT, float* W1T,
        const float* wv, const float* We, const float* be, float* embs) {
    __shared__ float smem[8 * 260];   // 8.3 KB; aliased per section
    int tid = threadIdx.x;
    int blk = blockIdx.x;
    if (blk < G_KA) {
        // ---- AbT[c][b] = inputs[b,:2048] . W1[c,:2048], 8 c per block ----
        int c = tid & 7, b = tid >> 3;
        int c0 = blk * 8;
        float acc = 0.f;
        for (int kt = 0; kt < FEAT; kt += 256) {
            __syncthreads();
            {
                int r = tid >> 5, cb = (tid & 31) * 8;
                const float* src = W1 + (size_t)(c0 + r) * W1C + kt + cb;
                float4 a0 = *(const float4*)src;
                float4 a1 = *(const float4*)(src + 4);
                *(float4*)&smem[r * 260 + cb] = a0;
                *(float4*)&smem[r * 260 + cb + 4] = a1;
            }
            __syncthreads();
            const float* xr = inp + (size_t)b * FEAT + kt;
#pragma unroll 8
            for (int k4 = 0; k4 < 64; k4++) {
                float4 x = *(const float4*)(xr + k4 * 4);
                float4 w = *(const float4*)&smem[c * 260 + k4 * 4];
                acc += x.x * w.x + x.y * w.y + x.z * w.z + x.w * w.w;
            }
        }
        AbT[(c0 + c) * B + b] = acc;
    } else if (blk < G_KA + G_W1T) {
        int lb = blk - G_KA;
        int c0 = (lb % 16) * 32, k0 = (lb / 16) * 32;
        float (*tile)[33] = (float(*)[33])smem;
        int kl = tid & 31, cl4 = tid >> 5;
#pragma unroll
        for (int p = 0; p < 4; p++) {
            int c = cl4 + p * 8;
            int k = k0 + kl;
            if (k < WVD) tile[c][kl] = W1[(size_t)(c0 + c) * W1C + FEAT + k];
        }
        __syncthreads();
        int cl = tid & 31, kl4 = tid >> 5;
#pragma unroll
        for (int p = 0; p < 4; p++) {
            int kk = kl4 + p * 8;
            int k = k0 + kk;
            if (k < WVD) W1T[(size_t)k * H1 + c0 + cl] = tile[cl][kk];
        }
    } else if (blk < G_KA + G_W1T + G_EMB) {
        // ---- embs: wave per (n,c), lanes over k (coalesced both operands) ----
        int lb = blk - G_KA - G_W1T;
        int wid = lb * 4 + (tid >> 6);
        int lane = tid & 63;
        int n = wid / EMB, c = wid - n * EMB;
        const float* xr = wv + (size_t)n * WVD;
        const float* wr = We + (size_t)c * WVD;
        float acc = 0.f;
#pragma unroll
        for (int i = 0; i < 5; i++) {
            int k = i * 64 + lane;
            if (k < WVD) acc += xr[k] * wr[k];
        }
        for (int m = 32; m; m >>= 1) acc += __shfl_xor(acc, m, 64);
        if (lane == 0) embs[n * EMB + c] = acc + be[c];
    } else {
        int lb = blk - G_KA - G_W1T - G_EMB;
        int wid = lb * 4 + (tid >> 6);
        int lane = tid & 63;
        int t = wid >> 14, u = (wid >> 4) & (N - 1), seg = wid & (SEG - 1);
        const int* eut = eu + t * E;
        int e0 = seg * SEGLEN, e1 = e0 + SEGLEN, cnt = 0;
        for (int c = e0; c < e1; c += 64) {
            int e = c + lane;
            bool ok = (e < e1) && (eut[e] == u);
            cnt += __popcll(__ballot(ok));
        }
        if (lane == 0) segcnt[wid] = cnt;
    }
}

// ============ F2: scan (1 block) | Wv GEMM | Ahat GEMM (32 nodes/block) ============
__global__ __launch_bounds__(256) void k_f2(
        const int* segcnt, int* segoff, int* counts, int* ptr,
        const float* wv, const float* W1T, float* Wvb,
        const float* embs, const float* RMbase, float* Ahat) {
    __shared__ float smemf[4096];   // 16 KB, aliased per role
    int tid = threadIdx.x, blk = blockIdx.x;
    if (blk == 0) {
        int* sc = (int*)smemf;
        for (int row = tid; row < 2048; row += 256) {
            int acc = 0;
            const int* src = segcnt + row * SEG;
            int* dst = segoff + row * SEG;
#pragma unroll
            for (int s = 0; s < SEG; s++) { dst[s] = acc; acc += src[s]; }
            counts[row] = acc;
            sc[row] = acc;
        }
        __syncthreads();
        int* src = sc; int* dst = sc + 2048;
        for (int st = 1; st < 2048; st <<= 1) {
            for (int j = tid; j < 2048; j += 256)
                dst[j] = src[j] + (j >= st ? src[j - st] : 0);
            __syncthreads();
            int* tmp = src; src = dst; dst = tmp;
        }
        for (int j = tid; j < 2048; j += 256)
            ptr[j] = j ? src[j - 1] : 0;
    } else if (blk <= G_WV2) {
        int lb = blk - 1;
        int c = (lb & 1) * 256 + tid;
        int n0 = (lb >> 1) * 8;
        float (*el)[WVD] = (float(*)[WVD])smemf;
        for (int idx = tid; idx < 8 * WVD; idx += 256)
            el[idx / WVD][idx % WVD] = wv[(size_t)(n0 + idx / WVD) * WVD + idx % WVD];
        __syncthreads();
        float acc[8] = {};
        for (int k = 0; k < WVD; k++) {
            float r = W1T[(size_t)k * H1 + c];
#pragma unroll
            for (int j = 0; j < 8; j++) acc[j] += el[j][k] * r;
        }
#pragma unroll
        for (int j = 0; j < 8; j++) Wvb[(size_t)(n0 + j) * H1 + c] = acc[j];
    } else {
        // ---- Ahat: 32 nodes per block, acc[32] in registers ----
        int lb = blk - 1 - G_WV2;
        int t = lb / (13 * 32), r = lb % (13 * 32);
        int bx = r % 13, by = r / 13;
        const float* RM = RMbase + (size_t)t * EMB * RC;
        float* Ah = Ahat + (size_t)t * N * RC;
        float (*el)[EMB] = (float(*)[EMB])smemf;   // [32][50]
        int n0 = by * 32;
        for (int i = tid; i < 32 * EMB; i += 256)
            el[i / EMB][i % EMB] = embs[(n0 + i / EMB) * EMB + i % EMB];
        __syncthreads();
        int m = bx * 256 + tid;
        if (m < RC) {
            float acc[32] = {};
            for (int c = 0; c < EMB; c++) {
                float rr = RM[(size_t)c * RC + m];
#pragma unroll
                for (int j = 0; j < 32; j++) acc[j] += el[j][c] * rr;
            }
#pragma unroll
            for (int j = 0; j < 32; j++) Ah[(size_t)(n0 + j) * RC + m] = acc[j];
        }
    }
}

// ============ F3: scatter only (zero LDS, full occupancy) ============
__global__ __launch_bounds__(256) void k_f3(
        const int* eu, const int* ev, const int* ptr, const int* segoff, int* sv) {
    int tid = threadIdx.x, blk = blockIdx.x;
    int wid = blk * 4 + (tid >> 6);
    int lane = tid & 63;
    int t = wid >> 14, u = (wid >> 4) & (N - 1), seg = wid & (SEG - 1);
    const int* eut = eu + t * E;
    const int* evt = ev + t * E;
    int row = t * N + u;
    int base = ptr[row] + segoff[row * SEG + seg];
    int e0 = seg * SEGLEN, e1 = e0 + SEGLEN, cnt = 0;
    for (int c = e0; c < e1; c += 64) {
        int e = c + lane;
        bool ok = (e < e1) && (eut[e] == u);
        unsigned long long m = __ballot(ok);
        if (ok) {
            int rank = __popcll(m & ((1ull << lane) - 1));
            sv[base + cnt + rank] = evt[e];
        }
        cnt += __popcll(m);
    }
}

// ============ F4: edge weights + norms (blocks 0..N-1) | inputnet (N..2N-1) ============
__global__ __launch_bounds__(256) void k_f4(
        const int* ptr, const int* counts, const int* sv,
        const float* embs, const float* Ahat, float* wbuf, float* inorm,
        const float* AbT, const float* Wvb, const float* b1,
        const float* W2, const float* b2, float* sT0) {
    __shared__ float smem[6656];   // 26 KB
    int tid = threadIdx.x;
    int blk = blockIdx.x;
    if (blk < N) {
        float* AL = smem;
        int u = blk;
        int wv_ = tid >> 6, k = tid & 63;
        float ssq = 0.f;
        for (int t = 0; t < T; t++) {
            __syncthreads();
            for (int idx = tid; idx < RC; idx += 256)
                AL[idx] = Ahat[((size_t)t * N + u) * RC + idx];
            __syncthreads();
            int base = ptr[t * N + u], cnt = counts[t * N + u];
            for (int i = wv_; i < cnt; i += 4) {
                int slot = base + i;
                int v = sv[slot];
                const float* vr = embs + v * EMB;
                float acc = 0.f;
#pragma unroll 10
                for (int d = 0; d < EMB; d++) acc += vr[d] * AL[d * 64 + k];
                wbuf[(size_t)slot * 64 + k] = acc;
                ssq += acc * acc;
            }
        }
        __syncthreads();
        AL[wv_ * 64 + k] = ssq;
        __syncthreads();
        if (tid < 64) {
            float tot = AL[tid] + AL[64 + tid] + AL[128 + tid] + AL[192 + tid];
            tot += __shfl_xor(tot, 1, 64);
            tot += __shfl_xor(tot, 2, 64);
            tot += __shfl_xor(tot, 4, 64);
            int ki = tid >> 3, kj = tid & 7;
            if (kj == 0) {
                float nv = sqrtf(tot);
                if (nv == 0.f) nv = 1.f;
                inorm[u * ND + ki] = 1.0f / nv;
            }
        }
    } else {
        int n = blk - N;
        float* w2s  = smem;            // 4096
        float* wvs  = smem + 4096;     // 512
        float* part = smem + 4608;     // 2048
        for (int idx = tid; idx < 8 * H1; idx += 256) w2s[idx] = W2[idx];
        for (int idx = tid; idx < H1; idx += 256)
            wvs[idx] = Wvb[(size_t)n * H1 + idx] + b1[idx];
        __syncthreads();
        int b = tid & 31, s = tid >> 5;
        float acc[8] = {};
        for (int i = 0; i < 64; i++) {
            int c = s * 64 + i;
            float tv = fmaxf(AbT[c * 32 + b] + wvs[c], 0.f);
#pragma unroll
            for (int ki = 0; ki < 8; ki++) acc[ki] += tv * w2s[ki * H1 + c];
        }
#pragma unroll
        for (int ki = 0; ki < 8; ki++) part[s * 256 + ki * 32 + b] = acc[ki];
        __syncthreads();
        int ki2 = tid >> 5, b2i = tid & 31;
        float tot = b2[ki2];
#pragma unroll
        for (int s2 = 0; s2 < 8; s2++) tot += part[s2 * 256 + ki2 * 32 + b2i];
        sT0[(size_t)n * 256 + tid] = tot;   // = sT0[(n*8+ki)*B + b]
    }
}

// ============ propagation step: barrier-free SpMM + GRU; last fuses outnet ============
__global__ __launch_bounds__(256) void k_step(
        const int* ptr, const int* counts, const int* sv,
        const float* wbuf, const float* inorm, const float* sT, int s,
        const float* W_ih, const float* W_hh, const float* b_ih, const float* b_hh,
        const float* Wo1, const float* bo1, const float* Wo2, const float* bo2,
        float* sOut, float* out, int last) {
    __shared__ float xs[256], hs[256], hfin[256];
    __shared__ float wih[192], whh[192];
    __shared__ float w1s[160], b1s[20], w2s[20];
    __shared__ float res[8][33];
    int tid = threadIdx.x;
    int u = blockIdx.x;
    int ki = tid >> 5, b = tid & 31;
    if (tid < 192) { wih[tid] = W_ih[tid]; whh[tid] = W_hh[tid]; }
    if (last) {
        if (tid < 160) w1s[tid] = Wo1[tid];
        if (tid < 20) { b1s[tid] = bo1[tid]; w2s[tid] = Wo2[tid]; }
    }
    const float* sIn = sT + (size_t)s * NDIM * B;
    float hown = sIn[((size_t)u * 8 + ki) * B + b];
    float acc = 0.f;
    for (int t = 0; t < T; t++) {
        int base = ptr[t * N + u], cnt = counts[t * N + u];
        for (int i = 0; i < cnt; i++) {
            int slot = base + i;
            int v = sv[slot];                      // block-uniform -> s_load
            const float* wp = wbuf + (size_t)slot * 64 + ki * 8;
            float4 wa = *(const float4*)wp;
            float4 wb = *(const float4*)(wp + 4);
            const float* ip = inorm + v * ND;      // uniform -> s_loads
            const float* hp = sIn + (size_t)v * 256 + b;
            acc += (wa.x * ip[0]) * hp[0]
                 + (wa.y * ip[1]) * hp[32]
                 + (wa.z * ip[2]) * hp[64]
                 + (wa.w * ip[3]) * hp[96]
                 + (wb.x * ip[4]) * hp[128]
                 + (wb.y * ip[5]) * hp[160]
                 + (wb.z * ip[6]) * hp[192]
                 + (wb.w * ip[7]) * hp[224];
        }
    }
    float xv = tanhf(acc);
    xs[ki * 32 + b] = xv;
    hs[ki * 32 + b] = hown;
    __syncthreads();
    float gr = b_ih[ki], gz = b_ih[8 + ki], gn = b_ih[16 + ki];
    float hr = b_hh[ki], hz = b_hh[8 + ki], hn = b_hh[16 + ki];
#pragma unroll
    for (int j = 0; j < 8; j++) {
        float xj = xs[j * 32 + b], hj = hs[j * 32 + b];
        gr += wih[ki * 8 + j] * xj;
        gz += wih[(8 + ki) * 8 + j] * xj;
        gn += wih[(16 + ki) * 8 + j] * xj;
        hr += whh[ki * 8 + j] * hj;
        hz += whh[(8 + ki) * 8 + j] * hj;
        hn += whh[(16 + ki) * 8 + j] * hj;
    }
    float r = 1.f / (1.f + expf(-(gr + hr)));
    float z = 1.f / (1.f + expf(-(gz + hz)));
    float nn = tanhf(gn + r * hn);
    float hnew = (1.f - z) * nn + z * hown;
    if (!last) {
        sOut[((size_t)u * 8 + ki) * B + b] = hnew;
        return;
    }
    hfin[ki * 32 + b] = hnew;
    __syncthreads();
    int s6 = tid >> 5, bb = tid & 31;
    if (s6 < 6) {
        float x[8];
#pragma unroll
        for (int kk = 0; kk < 8; kk++)
            x[kk] = (s6 < STEPS)
                ? sT[((size_t)s6 * NDIM + u * 8 + kk) * B + bb]
                : hfin[kk * 32 + bb];
        float accv = bo2[0];
#pragma unroll
        for (int j = 0; j < 20; j++) {
            float h = b1s[j];
#pragma unroll
            for (int kk = 0; kk < 8; kk++) h += w1s[j * 8 + kk] * x[kk];
            h = fmaxf(h, 0.f);
            accv += w2s[j] * h;
        }
        res[s6][bb] = accv;
    }
    __syncthreads();
    if (tid < 192) {
        int b_w = tid / 6, s_w = tid - b_w * 6;
        out[(size_t)b_w * ((STEPS + 1) * N) + u * (STEPS + 1) + s_w] = res[s_w][b_w];
    }
}

extern "C" void kernel_launch(void* const* d_in, const int* in_sizes, int n_in,
                              void* d_out, int out_size, void* d_ws, size_t ws_size,
                              hipStream_t stream) {
    const float* inputs   = (const float*)d_in[0];
    const float* wordvecs = (const float*)d_in[1];
    const int*   edge_u   = (const int*)d_in[2];
    const int*   edge_v   = (const int*)d_in[3];
    const float* W_in1 = (const float*)d_in[6];
    const float* b_in1 = (const float*)d_in[7];
    const float* W_in2 = (const float*)d_in[8];
    const float* b_in2 = (const float*)d_in[9];
    const float* W_emb = (const float*)d_in[10];
    const float* b_emb = (const float*)d_in[11];
    const float* rel_mats = (const float*)d_in[12];
    const float* W_ih = (const float*)d_in[13];
    const float* W_hh = (const float*)d_in[14];
    const float* b_ih = (const float*)d_in[15];
    const float* b_hh = (const float*)d_in[16];
    const float* W_o1 = (const float*)d_in[17];
    const float* b_o1 = (const float*)d_in[18];
    const float* W_o2 = (const float*)d_in[19];
    const float* b_o2 = (const float*)d_in[20];
    float* out = (float*)d_out;

    char* ws = (char*)d_ws;
    size_t off = 0;
    auto alloc = [&](size_t bytes) -> void* {
        void* p = ws + off;
        off = (off + bytes + 255) & ~(size_t)255;
        return p;
    };
    int* segcnt    = (int*)alloc((size_t)T * N * SEG * 4);
    int* segoff    = (int*)alloc((size_t)T * N * SEG * 4);
    int* counts    = (int*)alloc(2048 * 4);
    int* ptr       = (int*)alloc(2048 * 4);
    int* sv        = (int*)alloc((size_t)T * E * 4);
    float* inorm   = (float*)alloc((size_t)NDIM * 4);
    float* AbT     = (float*)alloc((size_t)H1 * B * 4);
    float* W1T     = (float*)alloc((size_t)WVD * H1 * 4);
    float* Wvb     = (float*)alloc((size_t)N * H1 * 4);
    float* embs    = (float*)alloc((size_t)N * EMB * 4);
    float* Ahat    = (float*)alloc((size_t)T * N * RC * 4);
    float* wbuf    = (float*)alloc((size_t)T * E * 64 * 4);
    float* sT      = (float*)alloc((size_t)(STEPS + 1) * NDIM * B * 4);

    k_f1<<<F1_TOT, 256, 0, stream>>>(edge_u, segcnt, inputs, W_in1, AbT, W1T,
                                     wordvecs, W_emb, b_emb, embs);
    k_f2<<<F2_TOT, 256, 0, stream>>>(segcnt, segoff, counts, ptr,
                                     wordvecs, W1T, Wvb, embs, rel_mats, Ahat);
    k_f3<<<T * N * SEG / 4, 256, 0, stream>>>(edge_u, edge_v, ptr, segoff, sv);
    k_f4<<<F4_TOT, 256, 0, stream>>>(ptr, counts, sv, embs, Ahat, wbuf, inorm,
                                     AbT, Wvb, b_in1, W_in2, b_in2, sT);

    for (int s = 0; s < STEPS; s++) {
        int last = (s == STEPS - 1) ? 1 : 0;
        k_step<<<N, 256, 0, stream>>>(ptr, counts, sv, wbuf, inorm, sT, s,
                                      W_ih, W_hh, b_ih, b_hh,
                                      W_o1, b_o1, W_o2, b_o2,
                                      sT + (size_t)(s + 1) * NDIM * B, out, last);
    }
}